// Round 1
// baseline (100.318 us; speedup 1.0000x reference)
//
#include <hip/hip_runtime.h>

// ConsolidateBits: pack every 32 consecutive (x > 0.5) predicates along the
// flat array into one uint32 word (bit i -> position i).
//
// Memory-bound: 512 MiB read + 16 MiB write. Strategy:
//   - lane loads float4 (16B coalesced; wave reads 1KiB contiguous)
//   - nibble = 4 predicates packed, shifted to 4*(lane&7)
//   - 8-lane OR-reduce via __shfl_xor(1|2|4) -> full 32-bit word
//   - lane with (lane&7)==0 stores the word (8 consecutive words per wave)

__global__ __launch_bounds__(256) void ConsolidateBits_35888746725585_kernel(
    const float* __restrict__ x,
    unsigned int* __restrict__ out,
    long long n_elems) {
    const int lane = threadIdx.x & 63;
    const long long tid    = (long long)blockIdx.x * blockDim.x + threadIdx.x;
    const long long stride = (long long)gridDim.x * blockDim.x;  // total threads

    // Each thread consumes 4 consecutive floats per step.
    for (long long e = 4 * tid; e < n_elems; e += 4 * stride) {
        const float4 v = *reinterpret_cast<const float4*>(x + e);
        unsigned int nib =
            (unsigned int)(v.x > 0.5f)        |
            ((unsigned int)(v.y > 0.5f) << 1) |
            ((unsigned int)(v.z > 0.5f) << 2) |
            ((unsigned int)(v.w > 0.5f) << 3);
        unsigned int word = nib << (4 * (lane & 7));
        // OR-reduce across the 8-lane group (32 consecutive elements).
        word |= __shfl_xor(word, 1);
        word |= __shfl_xor(word, 2);
        word |= __shfl_xor(word, 4);
        if ((lane & 7) == 0) {
            out[e >> 5] = word;  // e is 32-aligned here
        }
    }
}

extern "C" void kernel_launch(void* const* d_in, const int* in_sizes, int n_in,
                              void* d_out, int out_size, void* d_ws, size_t ws_size,
                              hipStream_t stream) {
    const float* x = (const float*)d_in[0];
    unsigned int* out = (unsigned int*)d_out;
    const long long n_elems = (long long)in_sizes[0];  // 4096*32768 = 134217728

    const int threads = 256;
    // Memory-bound: cap grid ~2048 blocks and grid-stride the rest (G11).
    const int blocks = 2048;
    hipLaunchKernelGGL(ConsolidateBits_35888746725585_kernel,
                       dim3(blocks), dim3(threads), 0, stream,
                       x, out, n_elems);
}